// Round 32
// baseline (55.130 us; speedup 1.0000x reference)
//
#include <hip/hip_runtime.h>
#include <math.h>

#define BB 8
#define TT 2048
#define CC 1024
#define HH 64
constexpr float SC2 = 0.03125f * 1.4426950408889634f; // (1/sqrt(1024)) * log2(e)

typedef __attribute__((ext_vector_type(8))) short bf16x8;
typedef __attribute__((ext_vector_type(8))) short s16x8;
typedef __attribute__((ext_vector_type(4))) short s16x4;
typedef __attribute__((ext_vector_type(4))) float f32x4;

static __device__ __forceinline__ short f2bf(float f) {
    union { float f; unsigned u; } un; un.f = f;
    unsigned r = un.u + 0x7FFFu + ((un.u >> 16) & 1u); // RNE
    return (short)(r >> 16);
}
static __device__ __forceinline__ float bf2f(short h) {
    union { unsigned u; float f; } un; un.u = ((unsigned)(unsigned short)h) << 16;
    return un.f;
}
static __device__ __forceinline__ bf16x8 cat8(s16x4 lo, s16x4 hi) {
    return __builtin_shufflevector(lo, hi, 0, 1, 2, 3, 4, 5, 6, 7);
}

#define SOFTSYNC() do {                                         \
    asm volatile("s_waitcnt lgkmcnt(0)" ::: "memory");          \
    __builtin_amdgcn_s_barrier();                               \
    __builtin_amdgcn_sched_barrier(0);                          \
  } while (0)

// ---------------- Kernel 0: W -> FRAGMENT-ORDERED bf16 ----------------
__global__ __launch_bounds__(256) void wconv_frag(
    const float* __restrict__ Wk, const float* __restrict__ Wq, const float* __restrict__ Wv,
    short* __restrict__ wfrag)
{
    const int i = blockIdx.x * 256 + threadIdx.x;   // 0..24575
    const int lane = i & 63;
    int g = i >> 6;
    const int n = g % 3;  g /= 3;
    const int kk2 = g & 1; g >>= 1;
    const int ks = g & 15;
    const int wv = g >> 4;                          // 0..3

    const int lr = lane & 15, lg = lane >> 4;
    const int col = wv * 48 + n * 16 + lr;          // 0..191
    const int kb  = ks * 64 + kk2 * 32 + 4 * lg;

    const float* W = (col < 64) ? Wk : (col < 128) ? Wq : Wv;
    const int wr = (col < 64) ? col : (col < 128) ? col - 64 : col - 128;

    float4 lo = *reinterpret_cast<const float4*>(&W[(size_t)wr * CC + kb]);
    float4 hi = *reinterpret_cast<const float4*>(&W[(size_t)wr * CC + kb + 16]);
    s16x8 h = { f2bf(lo.x), f2bf(lo.y), f2bf(lo.z), f2bf(lo.w),
                f2bf(hi.x), f2bf(hi.y), f2bf(hi.z), f2bf(hi.w) };
    *reinterpret_cast<s16x8*>(&wfrag[(size_t)i * 8]) = h;
}

// ---------------- Kernel 1: qkv projection, BM=16, 4 blocks/CU, W frags global->reg ----------------
// 1024 blocks x 16 rows, 2-deep prefetch, A-only dbuf LDS (4.6KB), BK=64.
__global__ __launch_bounds__(256) void proj_fused(
    const float* __restrict__ x, const short* __restrict__ wfrag,
    short* __restrict__ ko, short* __restrict__ qo, short* __restrict__ vT)
{
    __shared__ short At[2][16][72];

    const int tid  = threadIdx.x;
    const int row0 = blockIdx.x * 16;
    const int wv = tid >> 6, lane = tid & 63;
    const int lr = lane & 15, lg = lane >> 4;

    const int ar  = tid >> 4;            // A row 0..15
    const int ac4 = (tid & 15) * 4;

    f32x4 acc[3] = {};
    float4 axA, axB;
    s16x8 bw[6];

#define PLA(AX, k0_) do {                                                              \
    AX = *reinterpret_cast<const float4*>(&x[(size_t)(row0 + ar) * CC + (k0_) + ac4]); \
  } while (0)

#define PWA(bf_, AX) do {                                                              \
    s16x4 h_ = { f2bf(AX.x), f2bf(AX.y), f2bf(AX.z), f2bf(AX.w) };                     \
    *reinterpret_cast<s16x4*>(&At[bf_][ar][ac4]) = h_;                                 \
  } while (0)

#define WLOAD(ks_) do {                                                                \
    _Pragma("unroll")                                                                  \
    for (int kk2 = 0; kk2 < 2; ++kk2)                                                  \
        _Pragma("unroll")                                                              \
        for (int n = 0; n < 3; ++n)                                                    \
            bw[kk2 * 3 + n] = *reinterpret_cast<const s16x8*>(                         \
                &wfrag[((((size_t)wv * 16 + (ks_)) * 2 + kk2) * 3 + n) * 512 + lane * 8]); \
  } while (0)

#define PCOMP(bf_, ks_) do {                                                           \
    _Pragma("unroll")                                                                  \
    for (int kk2 = 0; kk2 < 2; ++kk2) {                                                \
        const int kb_ = kk2 * 32 + 4 * lg;                                             \
        bf16x8 aF = cat8(*reinterpret_cast<const s16x4*>(&At[bf_][lr][kb_]),           \
                         *reinterpret_cast<const s16x4*>(&At[bf_][lr][kb_ + 16]));     \
        _Pragma("unroll")                                                              \
        for (int n = 0; n < 3; ++n)                                                    \
            acc[n] = __builtin_amdgcn_mfma_f32_16x16x32_bf16(                          \
                aF, *reinterpret_cast<bf16x8*>(&bw[kk2 * 3 + n]), acc[n], 0, 0, 0);    \
    }                                                                                  \
  } while (0)

    PLA(axA, 0);
    PLA(axB, 64);
    PWA(0, axA);
    SOFTSYNC();

#pragma unroll
    for (int ks = 0; ks < 16; ks += 2) {
        WLOAD(ks);
        if (ks + 2 < 16) PLA(axA, (ks + 2) * 64);
        PCOMP(0, ks);
        PWA(1, axB);
        SOFTSYNC();
        WLOAD(ks + 1);
        if (ks + 3 < 16) PLA(axB, (ks + 3) * 64);
        PCOMP(1, ks + 1);
        if (ks + 2 < 16) PWA(0, axA);
        SOFTSYNC();
    }
#undef PLA
#undef PWA
#undef WLOAD
#undef PCOMP

    const int bb = row0 >> 11;
    const int t0 = row0 & 2047;
#pragma unroll
    for (int n = 0; n < 3; ++n) {
        const int col0 = wv * 48 + n * 16;
        const int mat  = col0 >> 6;
        const int hcol = (col0 & 63) + lr;
        const int trow = 4 * lg;
        if (mat == 2) {
            s16x4 pk = { f2bf(acc[n][0]), f2bf(acc[n][1]),
                         f2bf(acc[n][2]), f2bf(acc[n][3]) };
            *reinterpret_cast<s16x4*>(&vT[((size_t)bb * HH + hcol) * TT + t0 + trow]) = pk;
        } else {
            short* o = (mat == 0) ? ko : qo;
#pragma unroll
            for (int j = 0; j < 4; ++j)
                o[(size_t)(row0 + trow + j) * HH + hcol] = f2bf(acc[n][j]);
        }
    }
}

// ---------------- Kernel 2: causal flash attention, parity-4 + XCD b-locality + defer-max ----------------
__global__ __launch_bounds__(256) void attn_split(
    const short* __restrict__ q, const short* __restrict__ k,
    const short* __restrict__ vT, short* __restrict__ opb16,
    float* __restrict__ mm, float* __restrict__ ll)
{
    __shared__ short kl[2][4096];  // [kv][h] swizzled
    __shared__ short vl[2][4096];  // [h][t]  swizzled

    const int tid = threadIdx.x;
    const int w = tid >> 6, lane = tid & 63;
    const int lr = lane & 15, lg = lane >> 4;

    const int idx = blockIdx.x;
    const int b = idx & 7;          // XCD-locality: one batch per XCD
    const int j = idx >> 3;
    int jq, s;
    if (j < 64) { jq = j >> 2;              s = j & 3; }
    else        { jq = 31 - ((j - 64) >> 2); s = j & 3; }
    const int cnt = (jq >= s) ? ((jq - s) >> 2) + 1 : 0;

    const short* qb = q  + ((size_t)b * TT + jq * 64 + w * 16) * HH;
    const short* kb = k  + (size_t)b * TT * HH;   // [t][h]
    const short* vb = vT + (size_t)b * HH * TT;   // [h][t]

    bf16x8 aQ[2];
#pragma unroll
    for (int k2 = 0; k2 < 2; ++k2)
        aQ[k2] = cat8(*reinterpret_cast<const s16x4*>(&qb[lr * HH + k2 * 32 + 4 * lg]),
                      *reinterpret_cast<const s16x4*>(&qb[lr * HH + k2 * 32 + 16 + 4 * lg]));

    const int r0 = w * 16 + (lane >> 3);
    const int r1 = r0 + 8;
    const int c7 = lane & 7;
    const int swc = (c7 * 8) ^ ((r0 & 7) << 3);

    f32x4 o[4] = {};
    float m2 = -INFINITY, l_run = 0.f;

    s16x8 sk0, sk1, sv0, sv1;

#define LOADG(t_) do {                                                       \
    const short* kt_ = kb + (size_t)(t_) * 64 * HH;                          \
    const short* vt_ = vb + (t_) * 64;                                       \
    sk0 = *reinterpret_cast<const s16x8*>(&kt_[r0 * HH + c7 * 8]);           \
    sk1 = *reinterpret_cast<const s16x8*>(&kt_[r1 * HH + c7 * 8]);           \
    sv0 = *reinterpret_cast<const s16x8*>(&vt_[(size_t)r0 * TT + c7 * 8]);   \
    sv1 = *reinterpret_cast<const s16x8*>(&vt_[(size_t)r1 * TT + c7 * 8]);   \
  } while (0)

#define WRITELDS(bf_) do {                                                   \
    *reinterpret_cast<s16x8*>(&kl[bf_][r0 * 64 + swc]) = sk0;                \
    *reinterpret_cast<s16x8*>(&kl[bf_][r1 * 64 + swc]) = sk1;                \
    *reinterpret_cast<s16x8*>(&vl[bf_][r0 * 64 + swc]) = sv0;                \
    *reinterpret_cast<s16x8*>(&vl[bf_][r1 * 64 + swc]) = sv1;                \
  } while (0)

    if (cnt > 0) {
        LOADG(s);
        WRITELDS(0);
        SOFTSYNC();

        for (int u = 0; u < cnt; ++u) {
            const int cur = u & 1;
            const int jt = s + 4 * u;
            if (u + 1 < cnt) LOADG(jt + 4);

            f32x4 sv[4] = {};
#pragma unroll
            for (int k2 = 0; k2 < 2; ++k2)
#pragma unroll
                for (int n = 0; n < 4; ++n) {
                    const int row = n * 16 + lr;
                    const int sw = (row & 7) << 3;
                    s16x4 klo = *reinterpret_cast<const s16x4*>(&kl[cur][row * 64 + ((32 * k2 + 4 * lg) ^ sw)]);
                    s16x4 khi = *reinterpret_cast<const s16x4*>(&kl[cur][row * 64 + ((32 * k2 + 4 * lg + 16) ^ sw)]);
                    sv[n] = __builtin_amdgcn_mfma_f32_16x16x32_bf16(cat8(klo, khi), aQ[k2], sv[n], 0, 0, 0);
                }

            if (jt == jq) { // diag tile
#pragma unroll
                for (int n = 0; n < 4; ++n)
#pragma unroll
                    for (int jj = 0; jj < 4; ++jj)
                        if (n * 16 + 4 * lg + jj > w * 16 + lr) sv[n][jj] = -3.0e38f;
            }

            float tm = fmaxf(fmaxf(fmaxf(sv[0][0], sv[0][1]), fmaxf(sv[0][2], sv[0][3])),
                             fmaxf(fmaxf(sv[1][0], sv[1][1]), fmaxf(sv[1][2], sv[1][3])));
            tm = fmaxf(tm, fmaxf(fmaxf(fmaxf(sv[2][0], sv[2][1]), fmaxf(sv[2][2], sv[2][3])),
                                 fmaxf(fmaxf(sv[3][0], sv[3][1]), fmaxf(sv[3][2], sv[3][3]))));
            tm = fmaxf(tm, __shfl_xor(tm, 16));
            tm = fmaxf(tm, __shfl_xor(tm, 32));

            if (!__all((tm * SC2 - m2) <= 8.f)) {   // T13 defer-max
                const float mnew = fmaxf(m2, tm * SC2);
                const float alpha = exp2f(m2 - mnew);
                m2 = mnew;
                l_run *= alpha;
                float alj[4];
#pragma unroll
                for (int jj = 0; jj < 4; ++jj) alj[jj] = __shfl(alpha, 4 * lg + jj);
#pragma unroll
                for (int n = 0; n < 4; ++n)
#pragma unroll
                    for (int jj = 0; jj < 4; ++jj)
                        o[n][jj] *= alj[jj];
            }

            float psum = 0.f;
#pragma unroll
            for (int n = 0; n < 4; ++n)
#pragma unroll
                for (int jj = 0; jj < 4; ++jj) {
                    float p = exp2f(fmaf(sv[n][jj], SC2, -m2));
                    sv[n][jj] = p;
                    psum += p;
                }
            psum += __shfl_xor(psum, 16);
            psum += __shfl_xor(psum, 32);
            l_run += psum;

            bf16x8 aP[2];
#pragma unroll
            for (int k2 = 0; k2 < 2; ++k2) {
                bf16x8 tt;
#pragma unroll
                for (int jj = 0; jj < 4; ++jj) {
                    tt[jj]     = f2bf(sv[2 * k2][jj]);
                    tt[4 + jj] = f2bf(sv[2 * k2 + 1][jj]);
                }
                aP[k2] = tt;
            }
#pragma unroll
            for (int k2 = 0; k2 < 2; ++k2)
#pragma unroll
                for (int n = 0; n < 4; ++n) {
                    const int row = n * 16 + lr;
                    const int sw = (row & 7) << 3;
                    s16x4 vlo = *reinterpret_cast<const s16x4*>(&vl[cur][row * 64 + ((32 * k2 + 4 * lg) ^ sw)]);
                    s16x4 vhi = *reinterpret_cast<const s16x4*>(&vl[cur][row * 64 + ((32 * k2 + 4 * lg + 16) ^ sw)]);
                    o[n] = __builtin_amdgcn_mfma_f32_16x16x32_bf16(aP[k2], cat8(vlo, vhi), o[n], 0, 0, 0);
                }

            if (u + 1 < cnt) WRITELDS(cur ^ 1);
            SOFTSYNC();
        }
    }
#undef LOADG
#undef WRITELDS

    short* opb = opb16 + (((size_t)s * BB + b) * TT + jq * 64 + w * 16) * HH;
#pragma unroll
    for (int n = 0; n < 4; ++n)
#pragma unroll
        for (int jj = 0; jj < 4; ++jj)
            opb[(size_t)(4 * lg + jj) * HH + n * 16 + lr] = f2bf(o[n][jj]);
    if (lg == 0) {
        const size_t mi = ((size_t)s * BB + b) * TT + jq * 64 + w * 16 + lr;
        mm[mi] = m2;
        ll[mi] = l_run;
    }
}

// ---------------- Kernel 3: merge the four kv-parity partials (bf16 in, fp32 out) ----------------
__global__ __launch_bounds__(256) void attn_merge4(
    const short* __restrict__ opb16, const float* __restrict__ mm,
    const float* __restrict__ ll, float* __restrict__ out)
{
    const int t = blockIdx.x * 256 + threadIdx.x; // 65536
    const int row = t >> 2;
    const int seg = (t & 3) * 16;
    const size_t BT = (size_t)BB * TT;

    float mw[4], lw[4];
#pragma unroll
    for (int w = 0; w < 4; ++w) { mw[w] = mm[w * BT + row]; lw[w] = ll[w * BT + row]; }
    const float M = fmaxf(fmaxf(mw[0], mw[1]), fmaxf(mw[2], mw[3]));
    float ew[4], L = 0.f;
#pragma unroll
    for (int w = 0; w < 4; ++w) { ew[w] = exp2f(mw[w] - M); L += ew[w] * lw[w]; }
    const float inv = 1.f / L;

    float accv[16];
#pragma unroll
    for (int u = 0; u < 16; ++u) accv[u] = 0.f;
#pragma unroll
    for (int w = 0; w < 4; ++w) {
        const short* pb = opb16 + ((w * BT + row) * HH + seg);
        s16x8 v0 = *reinterpret_cast<const s16x8*>(pb);
        s16x8 v1 = *reinterpret_cast<const s16x8*>(pb + 8);
#pragma unroll
        for (int u = 0; u < 8; ++u) {
            accv[u]     += ew[w] * bf2f(v0[u]);
            accv[8 + u] += ew[w] * bf2f(v1[u]);
        }
    }
    float* po = out + (size_t)row * HH + seg;
#pragma unroll
    for (int u = 0; u < 4; ++u) {
        float4 rr = { accv[4 * u] * inv, accv[4 * u + 1] * inv,
                      accv[4 * u + 2] * inv, accv[4 * u + 3] * inv };
        *reinterpret_cast<float4*>(po + 4 * u) = rr;
    }
}

extern "C" void kernel_launch(void* const* d_in, const int* in_sizes, int n_in,
                              void* d_out, int out_size, void* d_ws, size_t ws_size,
                              hipStream_t stream) {
    const float* x  = (const float*)d_in[0];
    const float* Wk = (const float*)d_in[1];
    const float* Wq = (const float*)d_in[2];
    const float* Wv = (const float*)d_in[3];
    float* outp = (float*)d_out;

    const size_t n = (size_t)BB * TT * HH; // 1,048,576
    short* kbuf  = (short*)d_ws;
    short* qbuf  = kbuf + n;
    short* vbuf  = qbuf + n;                // vT layout [B][H][T]
    short* wfrag = vbuf + n;                // 196,608 bf16 weights (fragment-ordered)
    short* opb16 = wfrag + 196608;          // [4][B][T][H] bf16 partials (8 MB)
    float* mm    = (float*)(opb16 + 4 * n); // [4][B][T]
    float* ll    = mm + 4 * BB * TT;

    wconv_frag<<<96, 256, 0, stream>>>(Wk, Wq, Wv, wfrag);
    proj_fused<<<1024, 256, 0, stream>>>(x, wfrag, kbuf, qbuf, vbuf);
    attn_split<<<1024, 256, 0, stream>>>(qbuf, kbuf, vbuf, opb16, mm, ll);
    attn_merge4<<<256, 256, 0, stream>>>(opb16, mm, ll, outp);
}

// Round 33
// 46.433 us; speedup vs baseline: 1.1873x; 1.1873x over previous
//
#include <hip/hip_runtime.h>
#include <math.h>

#define BB 8
#define TT 2048
#define CC 1024
#define HH 64
constexpr float SC2 = 0.03125f * 1.4426950408889634f; // (1/sqrt(1024)) * log2(e)

typedef __attribute__((ext_vector_type(8))) short bf16x8;
typedef __attribute__((ext_vector_type(8))) short s16x8;
typedef __attribute__((ext_vector_type(4))) short s16x4;
typedef __attribute__((ext_vector_type(4))) float f32x4;

static __device__ __forceinline__ short f2bf(float f) {
    union { float f; unsigned u; } un; un.f = f;
    unsigned r = un.u + 0x7FFFu + ((un.u >> 16) & 1u); // RNE
    return (short)(r >> 16);
}
static __device__ __forceinline__ float bf2f(short h) {
    union { unsigned u; float f; } un; un.u = ((unsigned)(unsigned short)h) << 16;
    return un.f;
}
static __device__ __forceinline__ bf16x8 cat8(s16x4 lo, s16x4 hi) {
    return __builtin_shufflevector(lo, hi, 0, 1, 2, 3, 4, 5, 6, 7);
}

#define SOFTSYNC() do {                                         \
    asm volatile("s_waitcnt lgkmcnt(0)" ::: "memory");          \
    __builtin_amdgcn_s_barrier();                               \
    __builtin_amdgcn_sched_barrier(0);                          \
  } while (0)

// ---------------- Kernel 0: W -> FRAGMENT-ORDERED bf16 ----------------
// wfrag[wv][ks][kk2][n][lane][8]: lane's B-frag for (col-group wv*48+n*16, k-step ks,
// k-half kk2) is one contiguous 16B load. Same for every proj block (W shared).
__global__ __launch_bounds__(256) void wconv_frag(
    const float* __restrict__ Wk, const float* __restrict__ Wq, const float* __restrict__ Wv,
    short* __restrict__ wfrag)
{
    const int i = blockIdx.x * 256 + threadIdx.x;   // 0..24575
    const int lane = i & 63;
    int g = i >> 6;
    const int n = g % 3;  g /= 3;
    const int kk2 = g & 1; g >>= 1;
    const int ks = g & 15;
    const int wv = g >> 4;                          // 0..3

    const int lr = lane & 15, lg = lane >> 4;
    const int col = wv * 48 + n * 16 + lr;          // 0..191
    const int kb  = ks * 64 + kk2 * 32 + 4 * lg;

    const float* W = (col < 64) ? Wk : (col < 128) ? Wq : Wv;
    const int wr = (col < 64) ? col : (col < 128) ? col - 64 : col - 128;

    float4 lo = *reinterpret_cast<const float4*>(&W[(size_t)wr * CC + kb]);
    float4 hi = *reinterpret_cast<const float4*>(&W[(size_t)wr * CC + kb + 16]);
    s16x8 h = { f2bf(lo.x), f2bf(lo.y), f2bf(lo.z), f2bf(lo.w),
                f2bf(hi.x), f2bf(hi.y), f2bf(hi.z), f2bf(hi.w) };
    *reinterpret_cast<s16x8*>(&wfrag[(size_t)i * 8]) = h;
}

// ---------------- Kernel 1: qkv projection, W frags global->reg (no B LDS) ----------------
// 512 blocks x 32 rows, 2-deep x prefetch, A-only dbuf LDS (9KB).
__global__ __launch_bounds__(256) void proj_fused(
    const float* __restrict__ x, const short* __restrict__ wfrag,
    short* __restrict__ ko, short* __restrict__ qo, short* __restrict__ vT)
{
    __shared__ short At[2][32][72];

    const int tid  = threadIdx.x;
    const int row0 = blockIdx.x * 32;
    const int wv = tid >> 6, lane = tid & 63;
    const int lr = lane & 15, lg = lane >> 4;

    const int ar  = tid >> 4;            // A rows: ar, ar+16
    const int ac4 = (tid & 15) * 4;

    f32x4 acc[2][3] = {};
    float4 axA0, axA1, axB0, axB1;
    s16x8 bw[6];

#define PLA(AX0, AX1, k0_) do {                                                        \
    AX0 = *reinterpret_cast<const float4*>(&x[(size_t)(row0 + ar) * CC + (k0_) + ac4]);       \
    AX1 = *reinterpret_cast<const float4*>(&x[(size_t)(row0 + ar + 16) * CC + (k0_) + ac4]);  \
  } while (0)

#define PWA(bf_, AX0, AX1) do {                                                        \
    s16x4 h0 = { f2bf(AX0.x), f2bf(AX0.y), f2bf(AX0.z), f2bf(AX0.w) };                 \
    s16x4 h1 = { f2bf(AX1.x), f2bf(AX1.y), f2bf(AX1.z), f2bf(AX1.w) };                 \
    *reinterpret_cast<s16x4*>(&At[bf_][ar][ac4]) = h0;                                 \
    *reinterpret_cast<s16x4*>(&At[bf_][ar + 16][ac4]) = h1;                            \
  } while (0)

#define WLOAD(ks_) do {                                                                \
    _Pragma("unroll")                                                                  \
    for (int kk2 = 0; kk2 < 2; ++kk2)                                                  \
        _Pragma("unroll")                                                              \
        for (int n = 0; n < 3; ++n)                                                    \
            bw[kk2 * 3 + n] = *reinterpret_cast<const s16x8*>(                         \
                &wfrag[((((size_t)wv * 16 + (ks_)) * 2 + kk2) * 3 + n) * 512 + lane * 8]); \
  } while (0)

#define PCOMP(bf_) do {                                                                \
    _Pragma("unroll")                                                                  \
    for (int kk2 = 0; kk2 < 2; ++kk2) {                                                \
        bf16x8 aF[2];                                                                  \
        _Pragma("unroll")                                                              \
        for (int m = 0; m < 2; ++m) {                                                  \
            const int row_ = m * 16 + lr;                                              \
            aF[m] = cat8(*reinterpret_cast<const s16x4*>(&At[bf_][row_][kk2 * 32 + 4 * lg]), \
                         *reinterpret_cast<const s16x4*>(&At[bf_][row_][kk2 * 32 + 16 + 4 * lg])); \
        }                                                                              \
        _Pragma("unroll")                                                              \
        for (int m = 0; m < 2; ++m)                                                    \
            _Pragma("unroll")                                                          \
            for (int n = 0; n < 3; ++n)                                                \
                acc[m][n] = __builtin_amdgcn_mfma_f32_16x16x32_bf16(                   \
                    aF[m], *reinterpret_cast<bf16x8*>(&bw[kk2 * 3 + n]), acc[m][n], 0, 0, 0); \
    }                                                                                  \
  } while (0)

    PLA(axA0, axA1, 0);
    PLA(axB0, axB1, 64);
    PWA(0, axA0, axA1);
    SOFTSYNC();

#pragma unroll
    for (int ks = 0; ks < 16; ks += 2) {
        WLOAD(ks);
        if (ks + 2 < 16) PLA(axA0, axA1, (ks + 2) * 64);
        PCOMP(0);
        PWA(1, axB0, axB1);
        SOFTSYNC();
        WLOAD(ks + 1);
        if (ks + 3 < 16) PLA(axB0, axB1, (ks + 3) * 64);
        PCOMP(1);
        if (ks + 2 < 16) PWA(0, axA0, axA1);
        SOFTSYNC();
    }
#undef PLA
#undef PWA
#undef WLOAD
#undef PCOMP

    const int bb = row0 >> 11;
    const int t0 = row0 & 2047;
#pragma unroll
    for (int m = 0; m < 2; ++m)
#pragma unroll
        for (int n = 0; n < 3; ++n) {
            const int col0 = wv * 48 + n * 16;
            const int mat  = col0 >> 6;
            const int hcol = (col0 & 63) + lr;
            const int trow = m * 16 + 4 * lg;
            if (mat == 2) {
                s16x4 pk = { f2bf(acc[m][n][0]), f2bf(acc[m][n][1]),
                             f2bf(acc[m][n][2]), f2bf(acc[m][n][3]) };
                *reinterpret_cast<s16x4*>(&vT[((size_t)bb * HH + hcol) * TT + t0 + trow]) = pk;
            } else {
                short* o = (mat == 0) ? ko : qo;
#pragma unroll
                for (int j = 0; j < 4; ++j)
                    o[(size_t)(row0 + trow + j) * HH + hcol] = f2bf(acc[m][n][j]);
            }
        }
}

// ---------------- Kernel 2: causal flash attention, parity-4 + XCD b-locality + defer-max ----------------
__global__ __launch_bounds__(256) void attn_split(
    const short* __restrict__ q, const short* __restrict__ k,
    const short* __restrict__ vT, short* __restrict__ opb16,
    float* __restrict__ mm, float* __restrict__ ll)
{
    __shared__ short kl[2][4096];  // [kv][h] swizzled
    __shared__ short vl[2][4096];  // [h][t]  swizzled

    const int tid = threadIdx.x;
    const int w = tid >> 6, lane = tid & 63;
    const int lr = lane & 15, lg = lane >> 4;

    const int idx = blockIdx.x;
    const int b = idx & 7;          // XCD-locality: one batch per XCD
    const int j = idx >> 3;
    int jq, s;
    if (j < 64) { jq = j >> 2;              s = j & 3; }
    else        { jq = 31 - ((j - 64) >> 2); s = j & 3; }
    const int cnt = (jq >= s) ? ((jq - s) >> 2) + 1 : 0;

    const short* qb = q  + ((size_t)b * TT + jq * 64 + w * 16) * HH;
    const short* kb = k  + (size_t)b * TT * HH;   // [t][h]
    const short* vb = vT + (size_t)b * HH * TT;   // [h][t]

    bf16x8 aQ[2];
#pragma unroll
    for (int k2 = 0; k2 < 2; ++k2)
        aQ[k2] = cat8(*reinterpret_cast<const s16x4*>(&qb[lr * HH + k2 * 32 + 4 * lg]),
                      *reinterpret_cast<const s16x4*>(&qb[lr * HH + k2 * 32 + 16 + 4 * lg]));

    const int r0 = w * 16 + (lane >> 3);
    const int r1 = r0 + 8;
    const int c7 = lane & 7;
    const int swc = (c7 * 8) ^ ((r0 & 7) << 3);

    f32x4 o[4] = {};
    float m2 = -INFINITY, l_run = 0.f;

    s16x8 sk0, sk1, sv0, sv1;

#define LOADG(t_) do {                                                       \
    const short* kt_ = kb + (size_t)(t_) * 64 * HH;                          \
    const short* vt_ = vb + (t_) * 64;                                       \
    sk0 = *reinterpret_cast<const s16x8*>(&kt_[r0 * HH + c7 * 8]);           \
    sk1 = *reinterpret_cast<const s16x8*>(&kt_[r1 * HH + c7 * 8]);           \
    sv0 = *reinterpret_cast<const s16x8*>(&vt_[(size_t)r0 * TT + c7 * 8]);   \
    sv1 = *reinterpret_cast<const s16x8*>(&vt_[(size_t)r1 * TT + c7 * 8]);   \
  } while (0)

#define WRITELDS(bf_) do {                                                   \
    *reinterpret_cast<s16x8*>(&kl[bf_][r0 * 64 + swc]) = sk0;                \
    *reinterpret_cast<s16x8*>(&kl[bf_][r1 * 64 + swc]) = sk1;                \
    *reinterpret_cast<s16x8*>(&vl[bf_][r0 * 64 + swc]) = sv0;                \
    *reinterpret_cast<s16x8*>(&vl[bf_][r1 * 64 + swc]) = sv1;                \
  } while (0)

    if (cnt > 0) {
        LOADG(s);
        WRITELDS(0);
        SOFTSYNC();

        for (int u = 0; u < cnt; ++u) {
            const int cur = u & 1;
            const int jt = s + 4 * u;
            if (u + 1 < cnt) LOADG(jt + 4);

            f32x4 sv[4] = {};
#pragma unroll
            for (int k2 = 0; k2 < 2; ++k2)
#pragma unroll
                for (int n = 0; n < 4; ++n) {
                    const int row = n * 16 + lr;
                    const int sw = (row & 7) << 3;
                    s16x4 klo = *reinterpret_cast<const s16x4*>(&kl[cur][row * 64 + ((32 * k2 + 4 * lg) ^ sw)]);
                    s16x4 khi = *reinterpret_cast<const s16x4*>(&kl[cur][row * 64 + ((32 * k2 + 4 * lg + 16) ^ sw)]);
                    sv[n] = __builtin_amdgcn_mfma_f32_16x16x32_bf16(cat8(klo, khi), aQ[k2], sv[n], 0, 0, 0);
                }

            if (jt == jq) { // diag tile
#pragma unroll
                for (int n = 0; n < 4; ++n)
#pragma unroll
                    for (int jj = 0; jj < 4; ++jj)
                        if (n * 16 + 4 * lg + jj > w * 16 + lr) sv[n][jj] = -3.0e38f;
            }

            float tm = fmaxf(fmaxf(fmaxf(sv[0][0], sv[0][1]), fmaxf(sv[0][2], sv[0][3])),
                             fmaxf(fmaxf(sv[1][0], sv[1][1]), fmaxf(sv[1][2], sv[1][3])));
            tm = fmaxf(tm, fmaxf(fmaxf(fmaxf(sv[2][0], sv[2][1]), fmaxf(sv[2][2], sv[2][3])),
                                 fmaxf(fmaxf(sv[3][0], sv[3][1]), fmaxf(sv[3][2], sv[3][3]))));
            tm = fmaxf(tm, __shfl_xor(tm, 16));
            tm = fmaxf(tm, __shfl_xor(tm, 32));

            if (!__all((tm * SC2 - m2) <= 8.f)) {   // T13 defer-max
                const float mnew = fmaxf(m2, tm * SC2);
                const float alpha = exp2f(m2 - mnew);
                m2 = mnew;
                l_run *= alpha;
                float alj[4];
#pragma unroll
                for (int jj = 0; jj < 4; ++jj) alj[jj] = __shfl(alpha, 4 * lg + jj);
#pragma unroll
                for (int n = 0; n < 4; ++n)
#pragma unroll
                    for (int jj = 0; jj < 4; ++jj)
                        o[n][jj] *= alj[jj];
            }

            float psum = 0.f;
#pragma unroll
            for (int n = 0; n < 4; ++n)
#pragma unroll
                for (int jj = 0; jj < 4; ++jj) {
                    float p = exp2f(fmaf(sv[n][jj], SC2, -m2));
                    sv[n][jj] = p;
                    psum += p;
                }
            psum += __shfl_xor(psum, 16);
            psum += __shfl_xor(psum, 32);
            l_run += psum;

            bf16x8 aP[2];
#pragma unroll
            for (int k2 = 0; k2 < 2; ++k2) {
                bf16x8 tt;
#pragma unroll
                for (int jj = 0; jj < 4; ++jj) {
                    tt[jj]     = f2bf(sv[2 * k2][jj]);
                    tt[4 + jj] = f2bf(sv[2 * k2 + 1][jj]);
                }
                aP[k2] = tt;
            }
#pragma unroll
            for (int k2 = 0; k2 < 2; ++k2)
#pragma unroll
                for (int n = 0; n < 4; ++n) {
                    const int row = n * 16 + lr;
                    const int sw = (row & 7) << 3;
                    s16x4 vlo = *reinterpret_cast<const s16x4*>(&vl[cur][row * 64 + ((32 * k2 + 4 * lg) ^ sw)]);
                    s16x4 vhi = *reinterpret_cast<const s16x4*>(&vl[cur][row * 64 + ((32 * k2 + 4 * lg + 16) ^ sw)]);
                    o[n] = __builtin_amdgcn_mfma_f32_16x16x32_bf16(aP[k2], cat8(vlo, vhi), o[n], 0, 0, 0);
                }

            if (u + 1 < cnt) WRITELDS(cur ^ 1);
            SOFTSYNC();
        }
    }
#undef LOADG
#undef WRITELDS

    short* opb = opb16 + (((size_t)s * BB + b) * TT + jq * 64 + w * 16) * HH;
#pragma unroll
    for (int n = 0; n < 4; ++n)
#pragma unroll
        for (int jj = 0; jj < 4; ++jj)
            opb[(size_t)(4 * lg + jj) * HH + n * 16 + lr] = f2bf(o[n][jj]);
    if (lg == 0) {
        const size_t mi = ((size_t)s * BB + b) * TT + jq * 64 + w * 16 + lr;
        mm[mi] = m2;
        ll[mi] = l_run;
    }
}

// ---------------- Kernel 3: merge the four kv-parity partials (bf16 in, fp32 out) ----------------
__global__ __launch_bounds__(256) void attn_merge4(
    const short* __restrict__ opb16, const float* __restrict__ mm,
    const float* __restrict__ ll, float* __restrict__ out)
{
    const int t = blockIdx.x * 256 + threadIdx.x; // 65536
    const int row = t >> 2;
    const int seg = (t & 3) * 16;
    const size_t BT = (size_t)BB * TT;

    float mw[4], lw[4];
#pragma unroll
    for (int w = 0; w < 4; ++w) { mw[w] = mm[w * BT + row]; lw[w] = ll[w * BT + row]; }
    const float M = fmaxf(fmaxf(mw[0], mw[1]), fmaxf(mw[2], mw[3]));
    float ew[4], L = 0.f;
#pragma unroll
    for (int w = 0; w < 4; ++w) { ew[w] = exp2f(mw[w] - M); L += ew[w] * lw[w]; }
    const float inv = 1.f / L;

    float accv[16];
#pragma unroll
    for (int u = 0; u < 16; ++u) accv[u] = 0.f;
#pragma unroll
    for (int w = 0; w < 4; ++w) {
        const short* pb = opb16 + ((w * BT + row) * HH + seg);
        s16x8 v0 = *reinterpret_cast<const s16x8*>(pb);
        s16x8 v1 = *reinterpret_cast<const s16x8*>(pb + 8);
#pragma unroll
        for (int u = 0; u < 8; ++u) {
            accv[u]     += ew[w] * bf2f(v0[u]);
            accv[8 + u] += ew[w] * bf2f(v1[u]);
        }
    }
    float* po = out + (size_t)row * HH + seg;
#pragma unroll
    for (int u = 0; u < 4; ++u) {
        float4 rr = { accv[4 * u] * inv, accv[4 * u + 1] * inv,
                      accv[4 * u + 2] * inv, accv[4 * u + 3] * inv };
        *reinterpret_cast<float4*>(po + 4 * u) = rr;
    }
}

extern "C" void kernel_launch(void* const* d_in, const int* in_sizes, int n_in,
                              void* d_out, int out_size, void* d_ws, size_t ws_size,
                              hipStream_t stream) {
    const float* x  = (const float*)d_in[0];
    const float* Wk = (const float*)d_in[1];
    const float* Wq = (const float*)d_in[2];
    const float* Wv = (const float*)d_in[3];
    float* outp = (float*)d_out;

    const size_t n = (size_t)BB * TT * HH; // 1,048,576
    short* kbuf  = (short*)d_ws;
    short* qbuf  = kbuf + n;
    short* vbuf  = qbuf + n;                // vT layout [B][H][T]
    short* wfrag = vbuf + n;                // 196,608 bf16 weights (fragment-ordered)
    short* opb16 = wfrag + 196608;          // [4][B][T][H] bf16 partials (8 MB)
    float* mm    = (float*)(opb16 + 4 * n); // [4][B][T]
    float* ll    = mm + 4 * BB * TT;

    wconv_frag<<<96, 256, 0, stream>>>(Wk, Wq, Wv, wfrag);
    proj_fused<<<512, 256, 0, stream>>>(x, wfrag, kbuf, qbuf, vbuf);
    attn_split<<<1024, 256, 0, stream>>>(qbuf, kbuf, vbuf, opb16, mm, ll);
    attn_merge4<<<256, 256, 0, stream>>>(opb16, mm, ll, outp);
}